// Round 4
// baseline (39447.552 us; speedup 1.0000x reference)
//
#include <hip/hip_runtime.h>
#include <hip/hip_fp16.h>

#define NB 256
#define NT 1024
#define NH 256
#define NL 128
#define NV 13

typedef _Float16 h2t __attribute__((ext_vector_type(2)));
typedef _Float16 f16x8 __attribute__((ext_vector_type(8)));
typedef float f32x4 __attribute__((ext_vector_type(4)));

#define WS_WHH   0x0u       // u32[1024][128]  512KB  packed f16 W_hh
#define WS_WIH   0x80000u   // u32[1024][8]    32KB   packed f16 W_ih (padded 13->16)
#define WS_BIAS  0x88000u   // f32[1024]       4KB    b_ih+b_hh
#define WS_H0F   0x89000u   // f16[256][256]   128KB  h0
#define WS_LATF  0xA9000u   // u32[256][64]    64KB   packed f16 latent
#define WS_WNL   0xB9000u   // u32[256][192]   192KB  packed f16 W_nl
#define WS_WOUT  0xE9000u   // u32[16][128]    8KB    packed f16 W_out (padded 13->16 rows)
#define WS_HS    0x100000u  // f16[256][1024][256] = 128MB hidden states

__device__ __forceinline__ unsigned pk2(float a, float b){
  union { h2t h; unsigned u; } u;
  u.h.x = (_Float16)a; u.h.y = (_Float16)b;
  return u.u;
}

__device__ __forceinline__ float fdot2u(unsigned a, unsigned b, float c){
  union { unsigned u; h2t h; } ua, ub;
  ua.u = a; ub.u = b;
  return __builtin_amdgcn_fdot2(ua.h, ub.h, c, false);
}

__device__ __forceinline__ float sigm(float x){ return __builtin_amdgcn_rcpf(1.f + __expf(-x)); }
__device__ __forceinline__ float tanh_(float x){ return 2.f*__builtin_amdgcn_rcpf(1.f + __expf(-2.f*x)) - 1.f; }

// ---------------- prep: pack weights to f16 ----------------
__global__ void k_prep(const float* __restrict__ Wih, const float* __restrict__ Whh,
                       const float* __restrict__ bih, const float* __restrict__ bhh,
                       const float* __restrict__ Wnl, const float* __restrict__ Wout,
                       unsigned char* __restrict__ ws){
  unsigned* whh = (unsigned*)(ws + WS_WHH);
  unsigned* wih = (unsigned*)(ws + WS_WIH);
  float* bias   = (float*)(ws + WS_BIAS);
  unsigned* wnl = (unsigned*)(ws + WS_WNL);
  unsigned* wout= (unsigned*)(ws + WS_WOUT);
  int blk = blockIdx.x, tid = threadIdx.x;
  if (blk < 1024){
    int r = blk;
    if (tid < 128) whh[r*128+tid] = pk2(Whh[r*256+2*tid], Whh[r*256+2*tid+1]);
    if (tid < 8){
      int k0 = 2*tid, k1 = 2*tid+1;
      float a = (k0 < NV)? Wih[r*NV+k0] : 0.f;
      float b = (k1 < NV)? Wih[r*NV+k1] : 0.f;
      wih[r*8+tid] = pk2(a,b);
    }
    if (tid == 0) bias[r] = bih[r] + bhh[r];
  } else if (blk < 1280){
    int n = blk - 1024;
    for (int i = tid; i < 192; i += 128)
      wnl[n*192+i] = pk2(Wnl[n*384+2*i], Wnl[n*384+2*i+1]);
  } else {
    for (int i = tid; i < 2048; i += 128){
      int v = i >> 7; int p = (i & 127)*2;
      float a = (v < NV)? Wout[v*256+p]   : 0.f;
      float b = (v < NV)? Wout[v*256+p+1] : 0.f;
      wout[i] = pk2(a,b);
    }
  }
}

// ---------------- init: h0 = relu(lat @ W_lat^T + b), pack lat, zero out ----------------
__global__ void k_init(const float* __restrict__ lat, const float* __restrict__ Wlat,
                       const float* __restrict__ blat, unsigned char* __restrict__ ws,
                       float* __restrict__ out){
  __shared__ float sl[NL];
  int b = blockIdx.x, j = threadIdx.x;
  if (j < NL) sl[j] = lat[b*NL+j];
  __syncthreads();
  float a = blat[j];
  for (int k = 0; k < NL; ++k) a += Wlat[j*NL+k]*sl[k];
  float h0 = a > 0.f ? a : 0.f;
  __half* h0h    = (__half*)(ws + WS_H0F);
  unsigned* latf = (unsigned*)(ws + WS_LATF);
  h0h[b*256+j] = __float2half(h0);
  if (j < 64)  latf[b*64+j] = pk2(sl[2*j], sl[2*j+1]);
  if (j == 0)  out[b] = 0.f;
}

// ---------------- recurrent LSTM: 1 WG (256 thr, 4 waves) per batch element ----------------
// Thread j owns ALL FOUR gate rows of hidden unit j: rows j, j+256, j+512, j+768
// (i,f,g,o) -> cell update is thread-local, no gate exchange.
// W_hh row = 32 uint4 packed f16: chunks 0..23 in VGPRs (384 regs), 24..31 in LDS (128KB).
// 1 WG/CU (LDS-bound); __launch_bounds__(256,1) -> 512-reg budget in either arg2 semantics.
__global__ __launch_bounds__(256, 1)
void k_lstm(const float* __restrict__ seq, unsigned char* __restrict__ ws){
  __shared__ __align__(16) uint4 lws[8][4][256];   // 128KB: [chunk][gate][unit]
  __shared__ __align__(16) __half h2s[256];        // current h
  __shared__ __align__(16) unsigned xb[2][8];      // packed f16 x_t (13 padded to 16)
  int b = blockIdx.x, j = threadIdx.x;
  const uint4* whh4 = (const uint4*)(ws + WS_WHH);   // 32 uint4 per row
  const uint4* wih4 = (const uint4*)(ws + WS_WIH);   // 2 uint4 per row
  const float* bias = (const float*)(ws + WS_BIAS);
  const __half* h0h = (const __half*)(ws + WS_H0F);
  __half* hs = (__half*)(ws + WS_HS);

  uint4 wv[4][24];
  uint4 wx[4][2];
  float bb[4];
#pragma unroll
  for (int rr = 0; rr < 4; ++rr){
    int r = j + 256*rr;
#pragma unroll
    for (int q = 0; q < 24; ++q) wv[rr][q] = whh4[r*32+q];
#pragma unroll
    for (int q = 0; q < 8; ++q)  lws[q][rr][j] = whh4[r*32+24+q];
    wx[rr][0] = wih4[r*2]; wx[rr][1] = wih4[r*2+1];
    bb[rr] = bias[r];
  }
  h2s[j] = h0h[b*256+j];
  if (j < 8){
    int k0 = 2*j;
    const float* xp = seq + (size_t)b*NT*NV;
    float xa = (k0   < NV)? xp[k0]   : 0.f;
    float xc = (k0+1 < NV)? xp[k0+1] : 0.f;
    xb[0][j] = pk2(xa, xc);
  }
  float c = 0.f;
  // pin weights as opaque live registers (component-wise; zero instructions).
#pragma unroll
  for (int rr = 0; rr < 4; ++rr){
#pragma unroll
    for (int q = 0; q < 24; ++q)
      asm volatile("" : "+v"(wv[rr][q].x), "+v"(wv[rr][q].y), "+v"(wv[rr][q].z), "+v"(wv[rr][q].w));
    asm volatile("" : "+v"(wx[rr][0].x), "+v"(wx[rr][0].y), "+v"(wx[rr][0].z), "+v"(wx[rr][0].w));
    asm volatile("" : "+v"(wx[rr][1].x), "+v"(wx[rr][1].y), "+v"(wx[rr][1].z), "+v"(wx[rr][1].w));
  }
  __syncthreads();
  const uint4* h4 = (const uint4*)h2s;   // 32 uint4 of packed h

#pragma unroll 1
  for (int t = 0; t < NT; ++t){
    float a0[4], a1[4];
#pragma unroll
    for (int rr = 0; rr < 4; ++rr){ a0[rr] = bb[rr]; a1[rr] = 0.f; }
    {
      const uint4* xc4 = (const uint4*)xb[t & 1];
      uint4 x0 = xc4[0], x1 = xc4[1];
#pragma unroll
      for (int rr = 0; rr < 4; ++rr){
        a0[rr] = fdot2u(wx[rr][0].x, x0.x, a0[rr]); a1[rr] = fdot2u(wx[rr][0].y, x0.y, a1[rr]);
        a0[rr] = fdot2u(wx[rr][0].z, x0.z, a0[rr]); a1[rr] = fdot2u(wx[rr][0].w, x0.w, a1[rr]);
        a0[rr] = fdot2u(wx[rr][1].x, x1.x, a0[rr]); a1[rr] = fdot2u(wx[rr][1].y, x1.y, a1[rr]);
        a0[rr] = fdot2u(wx[rr][1].z, x1.z, a0[rr]);
      }
    }
#pragma unroll
    for (int q = 0; q < 24; ++q){
      uint4 hq = h4[q];                            // broadcast LDS read
#pragma unroll
      for (int rr = 0; rr < 4; ++rr){
        a0[rr] = fdot2u(wv[rr][q].x, hq.x, a0[rr]); a1[rr] = fdot2u(wv[rr][q].y, hq.y, a1[rr]);
        a0[rr] = fdot2u(wv[rr][q].z, hq.z, a0[rr]); a1[rr] = fdot2u(wv[rr][q].w, hq.w, a1[rr]);
      }
    }
#pragma unroll
    for (int q = 0; q < 8; ++q){
      uint4 hq = h4[24+q];
#pragma unroll
      for (int rr = 0; rr < 4; ++rr){
        uint4 wl = lws[q][rr][j];                  // lane-contiguous: conflict-free
        a0[rr] = fdot2u(wl.x, hq.x, a0[rr]); a1[rr] = fdot2u(wl.y, hq.y, a1[rr]);
        a0[rr] = fdot2u(wl.z, hq.z, a0[rr]); a1[rr] = fdot2u(wl.w, hq.w, a1[rr]);
      }
    }
    float gi = a0[0]+a1[0], gf = a0[1]+a1[1], gg = a0[2]+a1[2], go = a0[3]+a1[3];

    unsigned xpk = 0;
    bool doX = (j < 8) && (t+1 < NT);
    if (doX){
      int k0 = 2*j;
      const float* xp = seq + ((size_t)b*NT + (t+1))*NV;
      float xa = (k0   < NV)? xp[k0]   : 0.f;
      float xc2= (k0+1 < NV)? xp[k0+1] : 0.f;
      xpk = pk2(xa, xc2);
    }
    __syncthreads();                               // all h reads done
    c = sigm(gf)*c + sigm(gi)*tanh_(gg);
    float h = sigm(go)*tanh_(c);
    __half hh = __float2half(h);
    h2s[j] = hh;
    hs[((size_t)b*NT + t)*NH + j] = hh;
    if (doX) xb[(t+1) & 1][j] = xpk;
    __syncthreads();                               // new h visible
  }
}

// ---------------- projection + loss: f16 MFMA GEMM (M=128 tile, N=256, K=384) ----------------
struct __align__(16) SMp {
  union {
    struct { __half As[128][72]; __half Bs[256][72]; } s;   // staged tiles (pad 64->72)
    __half Zs[128][264];                                    // relu output (pad 256->264)
  } u;
  unsigned wout[16][128];
  float bnl[256];
  float bout[16];
  float logit[128][16];
  float red[128];
};

__global__ __launch_bounds__(512, 2)
void k_proj(const unsigned char* __restrict__ ws,
            const int* __restrict__ labels, const int* __restrict__ lengths,
            const float* __restrict__ bnl, const float* __restrict__ bout,
            float* __restrict__ out){
  __shared__ SMp sm;
  int tid = threadIdx.x;
  int mt = blockIdx.x;
  int m0 = mt*128;
  int b  = m0 >> 10;
  int t0 = m0 & 1023;
  const __half* hs      = (const __half*)(ws + WS_HS);
  const unsigned* latf  = (const unsigned*)(ws + WS_LATF);
  const unsigned* wnl   = (const unsigned*)(ws + WS_WNL);
  const unsigned* woutg = (const unsigned*)(ws + WS_WOUT);

  for (int i = tid; i < 2048; i += 512) ((unsigned*)sm.wout)[i] = woutg[i];
  if (tid < 256) sm.bnl[tid] = bnl[tid];
  if (tid < 16)  sm.bout[tid] = (tid < NV)? bout[tid] : 0.f;

  int wave = tid >> 6, lane = tid & 63;
  int wm = wave >> 2, wn = wave & 3;        // 2 x 4 wave grid, 64x64 per wave
  int l15 = lane & 15, l4 = lane >> 4;

  f32x4 acc[4][4];
  f32x4 zz = {0.f,0.f,0.f,0.f};
#pragma unroll
  for (int a = 0; a < 4; ++a)
#pragma unroll
    for (int q = 0; q < 4; ++q) acc[a][q] = zz;

#pragma unroll 1
  for (int kt = 0; kt < 6; ++kt){
#pragma unroll
    for (int it = 0; it < 2; ++it){           // stage A: 128 rows x 64 k (f16)
      int idx = it*512 + tid;
      int r = idx >> 3, ck = idx & 7;
      int k = kt*64 + ck*8;
      uint4 val;
      if (k < 256) val = *(const uint4*)&hs[((size_t)(m0+r))*NH + k];
      else         val = *(const uint4*)&latf[b*64 + (k-256)/2];
      *(uint4*)&sm.u.s.As[r][ck*8] = val;
    }
#pragma unroll
    for (int it = 0; it < 4; ++it){           // stage B: W_nl 256 rows x 64 k
      int idx = it*512 + tid;
      int n = idx >> 3, ck = idx & 7;
      int k = kt*64 + ck*8;
      uint4 val = *(const uint4*)&wnl[n*192 + k/2];
      *(uint4*)&sm.u.s.Bs[n][ck*8] = val;
    }
    __syncthreads();
#pragma unroll
    for (int kk = 0; kk < 2; ++kk){
      f16x8 af[4], bf[4];
#pragma unroll
      for (int mf = 0; mf < 4; ++mf) af[mf] = *(const f16x8*)&sm.u.s.As[wm*64+mf*16+l15][kk*32+l4*8];
#pragma unroll
      for (int nf = 0; nf < 4; ++nf) bf[nf] = *(const f16x8*)&sm.u.s.Bs[wn*64+nf*16+l15][kk*32+l4*8];
#pragma unroll
      for (int mf = 0; mf < 4; ++mf)
#pragma unroll
        for (int nf = 0; nf < 4; ++nf)
          acc[mf][nf] = __builtin_amdgcn_mfma_f32_16x16x32_f16(af[mf], bf[nf], acc[mf][nf], 0, 0, 0);
    }
    __syncthreads();
  }

  // epilogue: bias + relu -> Zs (f16)
#pragma unroll
  for (int mf = 0; mf < 4; ++mf)
#pragma unroll
    for (int nf = 0; nf < 4; ++nf)
#pragma unroll
      for (int e = 0; e < 4; ++e){
        int row = wm*64 + mf*16 + l4*4 + e;
        int col = wn*64 + nf*16 + l15;
        float v = acc[mf][nf][e] + sm.bnl[col];
        v = v > 0.f ? v : 0.f;
        sm.u.Zs[row][col] = __float2half(v);
      }
  __syncthreads();

  // GEMV: logits[r][v] = Z[r,:] . W_out[v,:] + b_out[v]; 4 threads per row, 4 v's each
  int r = tid >> 2, q = tid & 3;
  float la0 = sm.bout[q], la1 = sm.bout[q+4], la2 = sm.bout[q+8], la3 = sm.bout[q+12];
#pragma unroll
  for (int c8 = 0; c8 < 32; ++c8){
    uint4 zv = *(const uint4*)&sm.u.Zs[r][c8*8];
    uint4 w0 = *(const uint4*)&sm.wout[q][c8*4];
    uint4 w1 = *(const uint4*)&sm.wout[q+4][c8*4];
    uint4 w2 = *(const uint4*)&sm.wout[q+8][c8*4];
    uint4 w3 = *(const uint4*)&sm.wout[q+12][c8*4];
    la0 = fdot2u(w0.x, zv.x, la0); la0 = fdot2u(w0.y, zv.y, la0);
    la0 = fdot2u(w0.z, zv.z, la0); la0 = fdot2u(w0.w, zv.w, la0);
    la1 = fdot2u(w1.x, zv.x, la1); la1 = fdot2u(w1.y, zv.y, la1);
    la1 = fdot2u(w1.z, zv.z, la1); la1 = fdot2u(w1.w, zv.w, la1);
    la2 = fdot2u(w2.x, zv.x, la2); la2 = fdot2u(w2.y, zv.y, la2);
    la2 = fdot2u(w2.z, zv.z, la2); la2 = fdot2u(w2.w, zv.w, la2);
    la3 = fdot2u(w3.x, zv.x, la3); la3 = fdot2u(w3.y, zv.y, la3);
    la3 = fdot2u(w3.z, zv.z, la3); la3 = fdot2u(w3.w, zv.w, la3);
  }
  sm.logit[r][q] = la0; sm.logit[r][q+4] = la1; sm.logit[r][q+8] = la2; sm.logit[r][q+12] = la3;
  __syncthreads();

  if (tid < 128){
    int t = t0 + tid;
    float mx = -1e30f;
#pragma unroll
    for (int v = 0; v < NV; ++v) mx = fmaxf(mx, sm.logit[tid][v]);
    float s = 0.f;
#pragma unroll
    for (int v = 0; v < NV; ++v) s += __expf(sm.logit[tid][v] - mx);
    float lse = mx + __logf(s);
    int lab = labels[b*NT + t];
    float nll = lse - sm.logit[tid][lab];
    sm.red[tid] = (t < lengths[b])? nll : 0.f;
  }
  __syncthreads();
  if (tid < 64){
    float v = sm.red[tid] + sm.red[tid+64];
#pragma unroll
    for (int off = 32; off > 0; off >>= 1) v += __shfl_down(v, off);
    if (tid == 0) atomicAdd(out + b, v);
  }
}

extern "C" void kernel_launch(void* const* d_in, const int* in_sizes, int n_in,
                              void* d_out, int out_size, void* d_ws, size_t ws_size,
                              hipStream_t stream){
  const float* seq   = (const float*)d_in[0];
  const float* lat   = (const float*)d_in[1];
  const int* labels  = (const int*)d_in[2];
  const int* lengths = (const int*)d_in[3];
  const float* Wlat  = (const float*)d_in[4];
  const float* blat  = (const float*)d_in[5];
  const float* Wih   = (const float*)d_in[6];
  const float* Whh   = (const float*)d_in[7];
  const float* bih   = (const float*)d_in[8];
  const float* bhh   = (const float*)d_in[9];
  const float* Wnl   = (const float*)d_in[10];
  const float* bnl   = (const float*)d_in[11];
  const float* Wout  = (const float*)d_in[12];
  const float* bout  = (const float*)d_in[13];
  float* out = (float*)d_out;
  unsigned char* ws = (unsigned char*)d_ws;

  hipLaunchKernelGGL(k_prep, dim3(1281), dim3(128), 0, stream, Wih, Whh, bih, bhh, Wnl, Wout, ws);
  hipLaunchKernelGGL(k_init, dim3(256), dim3(256), 0, stream, lat, Wlat, blat, ws, out);
  hipLaunchKernelGGL(k_lstm, dim3(256), dim3(256), 0, stream, seq, ws);
  hipLaunchKernelGGL(k_proj, dim3(2048), dim3(512), 0, stream, ws, labels, lengths, bnl, bout, out);
}

// Round 5
// 3342.126 us; speedup vs baseline: 11.8031x; 11.8031x over previous
//
#include <hip/hip_runtime.h>
#include <hip/hip_fp16.h>

#define NB 256
#define NT 1024
#define NH 256
#define NL 128
#define NV 13

typedef _Float16 h2t __attribute__((ext_vector_type(2)));
typedef _Float16 f16x8 __attribute__((ext_vector_type(8)));
typedef float f32x4 __attribute__((ext_vector_type(4)));

#define WS_WHH   0x0u       // u32[1024][128]  512KB  packed f16 W_hh
#define WS_WIH   0x80000u   // u32[1024][8]    32KB   packed f16 W_ih (padded 13->16)
#define WS_BIAS  0x88000u   // f32[1024]       4KB    b_ih+b_hh
#define WS_H0F   0x89000u   // f16[256][256]   128KB  h0
#define WS_LATF  0xA9000u   // u32[256][64]    64KB   packed f16 latent
#define WS_WNL   0xB9000u   // u32[256][192]   192KB  packed f16 W_nl
#define WS_WOUT  0xE9000u   // u32[16][128]    8KB    packed f16 W_out (padded 13->16 rows)
#define WS_HS    0x100000u  // f16[256][1024][256] = 128MB hidden states

__device__ __forceinline__ unsigned pk2(float a, float b){
  union { h2t h; unsigned u; } u;
  u.h.x = (_Float16)a; u.h.y = (_Float16)b;
  return u.u;
}

__device__ __forceinline__ float fdot2u(unsigned a, unsigned b, float c){
  union { unsigned u; h2t h; } ua, ub;
  ua.u = a; ub.u = b;
  return __builtin_amdgcn_fdot2(ua.h, ub.h, c, false);
}

__device__ __forceinline__ float sigm(float x){ return __builtin_amdgcn_rcpf(1.f + __expf(-x)); }
__device__ __forceinline__ float tanh_(float x){ return 2.f*__builtin_amdgcn_rcpf(1.f + __expf(-2.f*x)) - 1.f; }

// ---------------- prep: pack weights to f16 ----------------
__global__ void k_prep(const float* __restrict__ Wih, const float* __restrict__ Whh,
                       const float* __restrict__ bih, const float* __restrict__ bhh,
                       const float* __restrict__ Wnl, const float* __restrict__ Wout,
                       unsigned char* __restrict__ ws){
  unsigned* whh = (unsigned*)(ws + WS_WHH);
  unsigned* wih = (unsigned*)(ws + WS_WIH);
  float* bias   = (float*)(ws + WS_BIAS);
  unsigned* wnl = (unsigned*)(ws + WS_WNL);
  unsigned* wout= (unsigned*)(ws + WS_WOUT);
  int blk = blockIdx.x, tid = threadIdx.x;
  if (blk < 1024){
    int r = blk;
    if (tid < 128) whh[r*128+tid] = pk2(Whh[r*256+2*tid], Whh[r*256+2*tid+1]);
    if (tid < 8){
      int k0 = 2*tid, k1 = 2*tid+1;
      float a = (k0 < NV)? Wih[r*NV+k0] : 0.f;
      float b = (k1 < NV)? Wih[r*NV+k1] : 0.f;
      wih[r*8+tid] = pk2(a,b);
    }
    if (tid == 0) bias[r] = bih[r] + bhh[r];
  } else if (blk < 1280){
    int n = blk - 1024;
    for (int i = tid; i < 192; i += 128)
      wnl[n*192+i] = pk2(Wnl[n*384+2*i], Wnl[n*384+2*i+1]);
  } else {
    for (int i = tid; i < 2048; i += 128){
      int v = i >> 7; int p = (i & 127)*2;
      float a = (v < NV)? Wout[v*256+p]   : 0.f;
      float b = (v < NV)? Wout[v*256+p+1] : 0.f;
      wout[i] = pk2(a,b);
    }
  }
}

// ---------------- init: h0 = relu(lat @ W_lat^T + b), pack lat, zero out ----------------
__global__ void k_init(const float* __restrict__ lat, const float* __restrict__ Wlat,
                       const float* __restrict__ blat, unsigned char* __restrict__ ws,
                       float* __restrict__ out){
  __shared__ float sl[NL];
  int b = blockIdx.x, j = threadIdx.x;
  if (j < NL) sl[j] = lat[b*NL+j];
  __syncthreads();
  float a = blat[j];
  for (int k = 0; k < NL; ++k) a += Wlat[j*NL+k]*sl[k];
  float h0 = a > 0.f ? a : 0.f;
  __half* h0h    = (__half*)(ws + WS_H0F);
  unsigned* latf = (unsigned*)(ws + WS_LATF);
  h0h[b*256+j] = __float2half(h0);
  if (j < 64)  latf[b*64+j] = pk2(sl[2*j], sl[2*j+1]);
  if (j == 0)  out[b] = 0.f;
}

// ---------------- recurrent LSTM: 1 WG (256 thr, 4 waves) per batch element ----------------
// Thread j owns gate rows j, j+256, j+512, j+768 (i,f,g,o): cell update thread-local.
// W_hh row = 32 uint4 packed f16 per row, split per row:
//   chunks 0..8   -> arch VGPRs (144 regs, asm-pinned)
//   chunks 9..22  -> AGPRs (224 regs, v_accvgpr_write once, v_accvgpr_read in loop;
//                    "a"-class pinned => cannot spill to scratch)
//   chunks 23..31 -> LDS (147KB, lane-contiguous conflict-free)
// 1 wave/SIMD => 512-reg unified budget (256 arch + 256 acc). Single barrier per
// step via double-buffered h.
__global__ __launch_bounds__(256, 1) __attribute__((amdgpu_waves_per_eu(1, 1)))
void k_lstm(const float* __restrict__ seq, unsigned char* __restrict__ ws){
  __shared__ __align__(16) uint4 lws[9][4][256];   // 147456B: [chunk][gate][unit]
  __shared__ __align__(16) __half h2s[2][256];     // double-buffered h
  __shared__ __align__(16) unsigned xb[2][8];      // packed f16 x_t (13 padded to 16)
  int b = blockIdx.x, j = threadIdx.x;
  const uint4* whh4 = (const uint4*)(ws + WS_WHH);   // 32 uint4 per row
  const uint4* wih4 = (const uint4*)(ws + WS_WIH);   // 2 uint4 per row
  const float* bias = (const float*)(ws + WS_BIAS);
  const __half* h0h = (const __half*)(ws + WS_H0F);
  __half* hs = (__half*)(ws + WS_HS);

  uint4 wv[4][9];
  unsigned ag[4][14][4];     // AGPR homes (fully unrolled -> SSA, class "a")
  uint4 wx[4][2];
  float bb[4];
#pragma unroll
  for (int rr = 0; rr < 4; ++rr){
    int r = j + 256*rr;
#pragma unroll
    for (int q = 0; q < 9; ++q) wv[rr][q] = whh4[r*32+q];
#pragma unroll
    for (int q = 0; q < 14; ++q){
      uint4 w = whh4[r*32+9+q];
      asm volatile("v_accvgpr_write_b32 %0, %1" : "=a"(ag[rr][q][0]) : "v"(w.x));
      asm volatile("v_accvgpr_write_b32 %0, %1" : "=a"(ag[rr][q][1]) : "v"(w.y));
      asm volatile("v_accvgpr_write_b32 %0, %1" : "=a"(ag[rr][q][2]) : "v"(w.z));
      asm volatile("v_accvgpr_write_b32 %0, %1" : "=a"(ag[rr][q][3]) : "v"(w.w));
    }
#pragma unroll
    for (int q = 0; q < 9; ++q) lws[q][rr][j] = whh4[r*32+23+q];
    wx[rr][0] = wih4[r*2]; wx[rr][1] = wih4[r*2+1];
    bb[rr] = bias[r];
  }
  h2s[0][j] = h0h[b*256+j];
  if (j < 8){
    int k0 = 2*j;
    const float* xp = seq + (size_t)b*NT*NV;
    float xa = (k0   < NV)? xp[k0]   : 0.f;
    float xc = (k0+1 < NV)? xp[k0+1] : 0.f;
    xb[0][j] = pk2(xa, xc);
  }
  float c = 0.f;
  // pin arch-VGPR weights as opaque live values (component-wise)
#pragma unroll
  for (int rr = 0; rr < 4; ++rr){
#pragma unroll
    for (int q = 0; q < 9; ++q)
      asm volatile("" : "+v"(wv[rr][q].x), "+v"(wv[rr][q].y), "+v"(wv[rr][q].z), "+v"(wv[rr][q].w));
    asm volatile("" : "+v"(wx[rr][0].x), "+v"(wx[rr][0].y), "+v"(wx[rr][0].z), "+v"(wx[rr][0].w));
    asm volatile("" : "+v"(wx[rr][1].x), "+v"(wx[rr][1].y), "+v"(wx[rr][1].z), "+v"(wx[rr][1].w));
  }
  __syncthreads();

#pragma unroll 1
  for (int t = 0; t < NT; ++t){
    // issue next-x global load early (hides under the ~1700cyc body)
    float xna = 0.f, xnc = 0.f;
    bool doX = (j < 8) && (t+1 < NT);
    if (doX){
      int k0 = 2*j;
      const float* xp = seq + ((size_t)b*NT + (t+1))*NV;
      xna = (k0   < NV)? xp[k0]   : 0.f;
      xnc = (k0+1 < NV)? xp[k0+1] : 0.f;
    }
    const uint4* hrd4 = (const uint4*)h2s[t & 1];
    float a0[4], a1[4];
#pragma unroll
    for (int rr = 0; rr < 4; ++rr){ a0[rr] = bb[rr]; a1[rr] = 0.f; }
    {
      const uint4* xc4 = (const uint4*)xb[t & 1];
      uint4 x0 = xc4[0], x1 = xc4[1];
#pragma unroll
      for (int rr = 0; rr < 4; ++rr){
        a0[rr] = fdot2u(wx[rr][0].x, x0.x, a0[rr]); a1[rr] = fdot2u(wx[rr][0].y, x0.y, a1[rr]);
        a0[rr] = fdot2u(wx[rr][0].z, x0.z, a0[rr]); a1[rr] = fdot2u(wx[rr][0].w, x0.w, a1[rr]);
        a0[rr] = fdot2u(wx[rr][1].x, x1.x, a0[rr]); a1[rr] = fdot2u(wx[rr][1].y, x1.y, a1[rr]);
        a0[rr] = fdot2u(wx[rr][1].z, x1.z, a0[rr]);
      }
    }
    // --- arch-VGPR chunks: k 0..143 ---
#pragma unroll
    for (int q = 0; q < 9; ++q){
      uint4 hq = hrd4[q];                          // broadcast LDS read
#pragma unroll
      for (int rr = 0; rr < 4; ++rr){
        a0[rr] = fdot2u(wv[rr][q].x, hq.x, a0[rr]); a1[rr] = fdot2u(wv[rr][q].y, hq.y, a1[rr]);
        a0[rr] = fdot2u(wv[rr][q].z, hq.z, a0[rr]); a1[rr] = fdot2u(wv[rr][q].w, hq.w, a1[rr]);
      }
    }
    // --- AGPR chunks: k 144..367 ---
#pragma unroll
    for (int q = 0; q < 14; ++q){
      uint4 hq = hrd4[9+q];
#pragma unroll
      for (int rr = 0; rr < 4; ++rr){
        unsigned t0, t1, t2, t3;
        asm volatile("v_accvgpr_read_b32 %0, %1" : "=v"(t0) : "a"(ag[rr][q][0]));
        asm volatile("v_accvgpr_read_b32 %0, %1" : "=v"(t1) : "a"(ag[rr][q][1]));
        asm volatile("v_accvgpr_read_b32 %0, %1" : "=v"(t2) : "a"(ag[rr][q][2]));
        asm volatile("v_accvgpr_read_b32 %0, %1" : "=v"(t3) : "a"(ag[rr][q][3]));
        a0[rr] = fdot2u(t0, hq.x, a0[rr]); a1[rr] = fdot2u(t1, hq.y, a1[rr]);
        a0[rr] = fdot2u(t2, hq.z, a0[rr]); a1[rr] = fdot2u(t3, hq.w, a1[rr]);
      }
    }
    // --- LDS chunks: k 368..511 ---
#pragma unroll
    for (int q = 0; q < 9; ++q){
      uint4 hq = hrd4[23+q];
#pragma unroll
      for (int rr = 0; rr < 4; ++rr){
        uint4 wl = lws[q][rr][j];                  // lane-contiguous: conflict-free
        a0[rr] = fdot2u(wl.x, hq.x, a0[rr]); a1[rr] = fdot2u(wl.y, hq.y, a1[rr]);
        a0[rr] = fdot2u(wl.z, hq.z, a0[rr]); a1[rr] = fdot2u(wl.w, hq.w, a1[rr]);
      }
    }
    float gi = a0[0]+a1[0], gf = a0[1]+a1[1], gg = a0[2]+a1[2], go = a0[3]+a1[3];
    c = sigm(gf)*c + sigm(gi)*tanh_(gg);
    float h = sigm(go)*tanh_(c);
    __half hh = __float2half(h);
    h2s[(t+1) & 1][j] = hh;                        // write other buffer
    hs[((size_t)b*NT + t)*NH + j] = hh;
    if (doX) xb[(t+1) & 1][j] = pk2(xna, xnc);
    __syncthreads();                               // single barrier per step
  }
}

// ---------------- projection + loss: f16 MFMA GEMM (M=128 tile, N=256, K=384) ----------------
struct __align__(16) SMp {
  union {
    struct { __half As[128][72]; __half Bs[256][72]; } s;   // staged tiles (pad 64->72)
    __half Zs[128][264];                                    // relu output (pad 256->264)
  } u;
  unsigned wout[16][128];
  float bnl[256];
  float bout[16];
  float logit[128][16];
  float red[128];
};

__global__ __launch_bounds__(512, 2)
void k_proj(const unsigned char* __restrict__ ws,
            const int* __restrict__ labels, const int* __restrict__ lengths,
            const float* __restrict__ bnl, const float* __restrict__ bout,
            float* __restrict__ out){
  __shared__ SMp sm;
  int tid = threadIdx.x;
  int mt = blockIdx.x;
  int m0 = mt*128;
  int b  = m0 >> 10;
  int t0 = m0 & 1023;
  const __half* hs      = (const __half*)(ws + WS_HS);
  const unsigned* latf  = (const unsigned*)(ws + WS_LATF);
  const unsigned* wnl   = (const unsigned*)(ws + WS_WNL);
  const unsigned* woutg = (const unsigned*)(ws + WS_WOUT);

  for (int i = tid; i < 2048; i += 512) ((unsigned*)sm.wout)[i] = woutg[i];
  if (tid < 256) sm.bnl[tid] = bnl[tid];
  if (tid < 16)  sm.bout[tid] = (tid < NV)? bout[tid] : 0.f;

  int wave = tid >> 6, lane = tid & 63;
  int wm = wave >> 2, wn = wave & 3;        // 2 x 4 wave grid, 64x64 per wave
  int l15 = lane & 15, l4 = lane >> 4;

  f32x4 acc[4][4];
  f32x4 zz = {0.f,0.f,0.f,0.f};
#pragma unroll
  for (int a = 0; a < 4; ++a)
#pragma unroll
    for (int q = 0; q < 4; ++q) acc[a][q] = zz;

#pragma unroll 1
  for (int kt = 0; kt < 6; ++kt){
#pragma unroll
    for (int it = 0; it < 2; ++it){           // stage A: 128 rows x 64 k (f16)
      int idx = it*512 + tid;
      int r = idx >> 3, ck = idx & 7;
      int k = kt*64 + ck*8;
      uint4 val;
      if (k < 256) val = *(const uint4*)&hs[((size_t)(m0+r))*NH + k];
      else         val = *(const uint4*)&latf[b*64 + (k-256)/2];
      *(uint4*)&sm.u.s.As[r][ck*8] = val;
    }
#pragma unroll
    for (int it = 0; it < 4; ++it){           // stage B: W_nl 256 rows x 64 k
      int idx = it*512 + tid;
      int n = idx >> 3, ck = idx & 7;
      int k = kt*64 + ck*8;
      uint4 val = *(const uint4*)&wnl[n*192 + k/2];
      *(uint4*)&sm.u.s.Bs[n][ck*8] = val;
    }
    __syncthreads();
#pragma unroll
    for (int kk = 0; kk < 2; ++kk){
      f16x8 af[4], bf[4];
#pragma unroll
      for (int mf = 0; mf < 4; ++mf) af[mf] = *(const f16x8*)&sm.u.s.As[wm*64+mf*16+l15][kk*32+l4*8];
#pragma unroll
      for (int nf = 0; nf < 4; ++nf) bf[nf] = *(const f16x8*)&sm.u.s.Bs[wn*64+nf*16+l15][kk*32+l4*8];
#pragma unroll
      for (int mf = 0; mf < 4; ++mf)
#pragma unroll
        for (int nf = 0; nf < 4; ++nf)
          acc[mf][nf] = __builtin_amdgcn_mfma_f32_16x16x32_f16(af[mf], bf[nf], acc[mf][nf], 0, 0, 0);
    }
    __syncthreads();
  }

  // epilogue: bias + relu -> Zs (f16)
#pragma unroll
  for (int mf = 0; mf < 4; ++mf)
#pragma unroll
    for (int nf = 0; nf < 4; ++nf)
#pragma unroll
      for (int e = 0; e < 4; ++e){
        int row = wm*64 + mf*16 + l4*4 + e;
        int col = wn*64 + nf*16 + l15;
        float v = acc[mf][nf][e] + sm.bnl[col];
        v = v > 0.f ? v : 0.f;
        sm.u.Zs[row][col] = __float2half(v);
      }
  __syncthreads();

  // GEMV: logits[r][v] = Z[r,:] . W_out[v,:] + b_out[v]; 4 threads per row, 4 v's each
  int r = tid >> 2, q = tid & 3;
  float la0 = sm.bout[q], la1 = sm.bout[q+4], la2 = sm.bout[q+8], la3 = sm.bout[q+12];
#pragma unroll
  for (int c8 = 0; c8 < 32; ++c8){
    uint4 zv = *(const uint4*)&sm.u.Zs[r][c8*8];
    uint4 w0 = *(const uint4*)&sm.wout[q][c8*4];
    uint4 w1 = *(const uint4*)&sm.wout[q+4][c8*4];
    uint4 w2 = *(const uint4*)&sm.wout[q+8][c8*4];
    uint4 w3 = *(const uint4*)&sm.wout[q+12][c8*4];
    la0 = fdot2u(w0.x, zv.x, la0); la0 = fdot2u(w0.y, zv.y, la0);
    la0 = fdot2u(w0.z, zv.z, la0); la0 = fdot2u(w0.w, zv.w, la0);
    la1 = fdot2u(w1.x, zv.x, la1); la1 = fdot2u(w1.y, zv.y, la1);
    la1 = fdot2u(w1.z, zv.z, la1); la1 = fdot2u(w1.w, zv.w, la1);
    la2 = fdot2u(w2.x, zv.x, la2); la2 = fdot2u(w2.y, zv.y, la2);
    la2 = fdot2u(w2.z, zv.z, la2); la2 = fdot2u(w2.w, zv.w, la2);
    la3 = fdot2u(w3.x, zv.x, la3); la3 = fdot2u(w3.y, zv.y, la3);
    la3 = fdot2u(w3.z, zv.z, la3); la3 = fdot2u(w3.w, zv.w, la3);
  }
  sm.logit[r][q] = la0; sm.logit[r][q+4] = la1; sm.logit[r][q+8] = la2; sm.logit[r][q+12] = la3;
  __syncthreads();

  if (tid < 128){
    int t = t0 + tid;
    float mx = -1e30f;
#pragma unroll
    for (int v = 0; v < NV; ++v) mx = fmaxf(mx, sm.logit[tid][v]);
    float s = 0.f;
#pragma unroll
    for (int v = 0; v < NV; ++v) s += __expf(sm.logit[tid][v] - mx);
    float lse = mx + __logf(s);
    int lab = labels[b*NT + t];
    float nll = lse - sm.logit[tid][lab];
    sm.red[tid] = (t < lengths[b])? nll : 0.f;
  }
  __syncthreads();
  if (tid < 64){
    float v = sm.red[tid] + sm.red[tid+64];
#pragma unroll
    for (int off = 32; off > 0; off >>= 1) v += __shfl_down(v, off);
    if (tid == 0) atomicAdd(out + b, v);
  }
}

extern "C" void kernel_launch(void* const* d_in, const int* in_sizes, int n_in,
                              void* d_out, int out_size, void* d_ws, size_t ws_size,
                              hipStream_t stream){
  const float* seq   = (const float*)d_in[0];
  const float* lat   = (const float*)d_in[1];
  const int* labels  = (const int*)d_in[2];
  const int* lengths = (const int*)d_in[3];
  const float* Wlat  = (const float*)d_in[4];
  const float* blat  = (const float*)d_in[5];
  const float* Wih   = (const float*)d_in[6];
  const float* Whh   = (const float*)d_in[7];
  const float* bih   = (const float*)d_in[8];
  const float* bhh   = (const float*)d_in[9];
  const float* Wnl   = (const float*)d_in[10];
  const float* bnl   = (const float*)d_in[11];
  const float* Wout  = (const float*)d_in[12];
  const float* bout  = (const float*)d_in[13];
  float* out = (float*)d_out;
  unsigned char* ws = (unsigned char*)d_ws;

  hipLaunchKernelGGL(k_prep, dim3(1281), dim3(128), 0, stream, Wih, Whh, bih, bhh, Wnl, Wout, ws);
  hipLaunchKernelGGL(k_init, dim3(256), dim3(256), 0, stream, lat, Wlat, blat, ws, out);
  hipLaunchKernelGGL(k_lstm, dim3(256), dim3(256), 0, stream, seq, ws);
  hipLaunchKernelGGL(k_proj, dim3(2048), dim3(512), 0, stream, ws, labels, lengths, bnl, bout, out);
}

// Round 6
// 2970.746 us; speedup vs baseline: 13.2787x; 1.1250x over previous
//
#include <hip/hip_runtime.h>
#include <hip/hip_fp16.h>

#define NB 256
#define NT 1024
#define NH 256
#define NL 128
#define NV 13

typedef _Float16 h2t __attribute__((ext_vector_type(2)));
typedef _Float16 f16x8 __attribute__((ext_vector_type(8)));
typedef float f32x4 __attribute__((ext_vector_type(4)));

#define WS_WHH   0x0u       // u32[1024][128]  512KB  packed f16 W_hh
#define WS_WIH   0x80000u   // u32[1024][8]    32KB   packed f16 W_ih (padded 13->16)
#define WS_BIAS  0x88000u   // f32[1024]       4KB    b_ih+b_hh
#define WS_H0F   0x89000u   // f16[256][256]   128KB  h0
#define WS_LATF  0xA9000u   // u32[256][64]    64KB   packed f16 latent
#define WS_WNL   0xB9000u   // u32[256][192]   192KB  packed f16 W_nl
#define WS_WOUT  0xE9000u   // u32[16][128]    8KB    packed f16 W_out (padded 13->16 rows)
#define WS_HS    0x100000u  // f16[256][1024][256] = 128MB hidden states

__device__ __forceinline__ unsigned pk2(float a, float b){
  union { h2t h; unsigned u; } u;
  u.h.x = (_Float16)a; u.h.y = (_Float16)b;
  return u.u;
}

__device__ __forceinline__ float fdot2u(unsigned a, unsigned b, float c){
  union { unsigned u; h2t h; } ua, ub;
  ua.u = a; ub.u = b;
  return __builtin_amdgcn_fdot2(ua.h, ub.h, c, false);
}

__device__ __forceinline__ float sigm(float x){ return __builtin_amdgcn_rcpf(1.f + __expf(-x)); }
__device__ __forceinline__ float tanh_(float x){ return 2.f*__builtin_amdgcn_rcpf(1.f + __expf(-2.f*x)) - 1.f; }

// ---------------- prep: pack weights to f16 ----------------
__global__ void k_prep(const float* __restrict__ Wih, const float* __restrict__ Whh,
                       const float* __restrict__ bih, const float* __restrict__ bhh,
                       const float* __restrict__ Wnl, const float* __restrict__ Wout,
                       unsigned char* __restrict__ ws){
  unsigned* whh = (unsigned*)(ws + WS_WHH);
  unsigned* wih = (unsigned*)(ws + WS_WIH);
  float* bias   = (float*)(ws + WS_BIAS);
  unsigned* wnl = (unsigned*)(ws + WS_WNL);
  unsigned* wout= (unsigned*)(ws + WS_WOUT);
  int blk = blockIdx.x, tid = threadIdx.x;
  if (blk < 1024){
    int r = blk;
    if (tid < 128) whh[r*128+tid] = pk2(Whh[r*256+2*tid], Whh[r*256+2*tid+1]);
    if (tid < 8){
      int k0 = 2*tid, k1 = 2*tid+1;
      float a = (k0 < NV)? Wih[r*NV+k0] : 0.f;
      float b = (k1 < NV)? Wih[r*NV+k1] : 0.f;
      wih[r*8+tid] = pk2(a,b);
    }
    if (tid == 0) bias[r] = bih[r] + bhh[r];
  } else if (blk < 1280){
    int n = blk - 1024;
    for (int i = tid; i < 192; i += 128)
      wnl[n*192+i] = pk2(Wnl[n*384+2*i], Wnl[n*384+2*i+1]);
  } else {
    for (int i = tid; i < 2048; i += 128){
      int v = i >> 7; int p = (i & 127)*2;
      float a = (v < NV)? Wout[v*256+p]   : 0.f;
      float b = (v < NV)? Wout[v*256+p+1] : 0.f;
      wout[i] = pk2(a,b);
    }
  }
}

// ---------------- init: h0 = relu(lat @ W_lat^T + b), pack lat, zero out ----------------
__global__ void k_init(const float* __restrict__ lat, const float* __restrict__ Wlat,
                       const float* __restrict__ blat, unsigned char* __restrict__ ws,
                       float* __restrict__ out){
  __shared__ float sl[NL];
  int b = blockIdx.x, j = threadIdx.x;
  if (j < NL) sl[j] = lat[b*NL+j];
  __syncthreads();
  float a = blat[j];
  for (int k = 0; k < NL; ++k) a += Wlat[j*NL+k]*sl[k];
  float h0 = a > 0.f ? a : 0.f;
  __half* h0h    = (__half*)(ws + WS_H0F);
  unsigned* latf = (unsigned*)(ws + WS_LATF);
  h0h[b*256+j] = __float2half(h0);
  if (j < 64)  latf[b*64+j] = pk2(sl[2*j], sl[2*j+1]);
  if (j == 0)  out[b] = 0.f;
}

// ---------------- recurrent LSTM: 1 WG (512 thr, 8 waves = 2/SIMD) per batch ----------------
// Thread j owns rows r0=j (i if j<256, f else) and r1=j+512 (g / o).
// W_hh row = 32 uint4 packed f16, split per row for a 128V+128A per-wave budget:
//   chunks 0..6   -> arch VGPRs (56 regs, component-pinned)
//   chunks 7..22  -> AGPRs (128 AGPRs exactly; v_accvgpr_write once, read in loop)
//   chunks 23..31 -> LDS (147KB, lane-contiguous conflict-free)
// 2 waves/SIMD: per-SIMD file = 512 slots = 2 x (128V + 128A). f/o gates exchanged
// through gts2; i/g stay local. 2 barriers/step.
__global__ __launch_bounds__(512) __attribute__((amdgpu_waves_per_eu(2, 2)))
void k_lstm(const float* __restrict__ seq, unsigned char* __restrict__ ws){
  __shared__ __align__(16) uint4 lws[9][2][512];   // 147456B: [chunk][row-half][tid]
  __shared__ __align__(16) __half h2s[256];        // current h
  __shared__ __align__(8)  float gts2[256][2];     // {f,o} pre-activations
  __shared__ __align__(16) unsigned xb[2][8];      // packed f16 x_t (13 padded to 16)
  int b = blockIdx.x, j = threadIdx.x;
  int r0 = j, r1 = j + 512;
  const uint4* whh4 = (const uint4*)(ws + WS_WHH);   // 32 uint4 per row
  const uint4* wih4 = (const uint4*)(ws + WS_WIH);   // 2 uint4 per row
  const float* bias = (const float*)(ws + WS_BIAS);
  const __half* h0h = (const __half*)(ws + WS_H0F);
  __half* hs = (__half*)(ws + WS_HS);

  uint4 wv[2][7];
  unsigned ag[2][16][4];     // AGPR homes: 2*16*4 = 128 AGPRs
  uint4 wx[2][2];
  float bb0, bb1;
#pragma unroll
  for (int rr = 0; rr < 2; ++rr){
    int r = (rr == 0)? r0 : r1;
#pragma unroll
    for (int q = 0; q < 7; ++q) wv[rr][q] = whh4[r*32+q];
#pragma unroll
    for (int q = 0; q < 16; ++q){
      uint4 w = whh4[r*32+7+q];
      asm volatile("v_accvgpr_write_b32 %0, %1" : "=a"(ag[rr][q][0]) : "v"(w.x));
      asm volatile("v_accvgpr_write_b32 %0, %1" : "=a"(ag[rr][q][1]) : "v"(w.y));
      asm volatile("v_accvgpr_write_b32 %0, %1" : "=a"(ag[rr][q][2]) : "v"(w.z));
      asm volatile("v_accvgpr_write_b32 %0, %1" : "=a"(ag[rr][q][3]) : "v"(w.w));
    }
#pragma unroll
    for (int q = 0; q < 9; ++q) lws[q][rr][j] = whh4[r*32+23+q];
    wx[rr][0] = wih4[r*2]; wx[rr][1] = wih4[r*2+1];
  }
  bb0 = bias[r0]; bb1 = bias[r1];
  if (j < 256) h2s[j] = h0h[b*256+j];
  if (j >= 256 && j < 264){
    int i2 = j - 256; int k0 = 2*i2;
    const float* xp = seq + (size_t)b*NT*NV;
    float xa = (k0   < NV)? xp[k0]   : 0.f;
    float xc = (k0+1 < NV)? xp[k0+1] : 0.f;
    xb[0][i2] = pk2(xa, xc);
  }
  float c = 0.f;
  // pin arch-VGPR weights as opaque live values (component-wise; zero instructions)
#pragma unroll
  for (int rr = 0; rr < 2; ++rr){
#pragma unroll
    for (int q = 0; q < 7; ++q)
      asm volatile("" : "+v"(wv[rr][q].x), "+v"(wv[rr][q].y), "+v"(wv[rr][q].z), "+v"(wv[rr][q].w));
    asm volatile("" : "+v"(wx[rr][0].x), "+v"(wx[rr][0].y), "+v"(wx[rr][0].z), "+v"(wx[rr][0].w));
    asm volatile("" : "+v"(wx[rr][1].x), "+v"(wx[rr][1].y), "+v"(wx[rr][1].z), "+v"(wx[rr][1].w));
  }
  __syncthreads();
  const uint4* h4 = (const uint4*)h2s;   // 32 uint4 of packed h

#pragma unroll 1
  for (int t = 0; t < NT; ++t){
    // issue next-x global load early (hides under the step body)
    float xna = 0.f, xnc = 0.f;
    bool doX = (j >= 256 && j < 264) && (t+1 < NT);
    if (doX){
      int k0 = 2*(j-256);
      const float* xp = seq + ((size_t)b*NT + (t+1))*NV;
      xna = (k0   < NV)? xp[k0]   : 0.f;
      xnc = (k0+1 < NV)? xp[k0+1] : 0.f;
    }
    float p00 = bb0, p01 = 0.f;
    float p10 = bb1, p11 = 0.f;
    {
      const uint4* xc4 = (const uint4*)xb[t & 1];
      uint4 x0 = xc4[0], x1 = xc4[1];
      p00 = fdot2u(wx[0][0].x, x0.x, p00); p01 = fdot2u(wx[0][0].y, x0.y, p01);
      p00 = fdot2u(wx[0][0].z, x0.z, p00); p01 = fdot2u(wx[0][0].w, x0.w, p01);
      p00 = fdot2u(wx[0][1].x, x1.x, p00); p01 = fdot2u(wx[0][1].y, x1.y, p01);
      p00 = fdot2u(wx[0][1].z, x1.z, p00);
      p10 = fdot2u(wx[1][0].x, x0.x, p10); p11 = fdot2u(wx[1][0].y, x0.y, p11);
      p10 = fdot2u(wx[1][0].z, x0.z, p10); p11 = fdot2u(wx[1][0].w, x0.w, p11);
      p10 = fdot2u(wx[1][1].x, x1.x, p10); p11 = fdot2u(wx[1][1].y, x1.y, p11);
      p10 = fdot2u(wx[1][1].z, x1.z, p10);
    }
    // --- arch-VGPR chunks: k 0..111 ---
#pragma unroll
    for (int q = 0; q < 7; ++q){
      uint4 hq = h4[q];                            // broadcast LDS read
      p00 = fdot2u(wv[0][q].x, hq.x, p00); p01 = fdot2u(wv[0][q].y, hq.y, p01);
      p00 = fdot2u(wv[0][q].z, hq.z, p00); p01 = fdot2u(wv[0][q].w, hq.w, p01);
      p10 = fdot2u(wv[1][q].x, hq.x, p10); p11 = fdot2u(wv[1][q].y, hq.y, p11);
      p10 = fdot2u(wv[1][q].z, hq.z, p10); p11 = fdot2u(wv[1][q].w, hq.w, p11);
    }
    // --- AGPR chunks: k 112..367 ---
#pragma unroll
    for (int q = 0; q < 16; ++q){
      uint4 hq = h4[7+q];
      unsigned t0, t1, t2, t3, t4, t5, t6, t7;
      asm volatile("v_accvgpr_read_b32 %0, %1" : "=v"(t0) : "a"(ag[0][q][0]));
      asm volatile("v_accvgpr_read_b32 %0, %1" : "=v"(t1) : "a"(ag[0][q][1]));
      asm volatile("v_accvgpr_read_b32 %0, %1" : "=v"(t2) : "a"(ag[0][q][2]));
      asm volatile("v_accvgpr_read_b32 %0, %1" : "=v"(t3) : "a"(ag[0][q][3]));
      asm volatile("v_accvgpr_read_b32 %0, %1" : "=v"(t4) : "a"(ag[1][q][0]));
      asm volatile("v_accvgpr_read_b32 %0, %1" : "=v"(t5) : "a"(ag[1][q][1]));
      asm volatile("v_accvgpr_read_b32 %0, %1" : "=v"(t6) : "a"(ag[1][q][2]));
      asm volatile("v_accvgpr_read_b32 %0, %1" : "=v"(t7) : "a"(ag[1][q][3]));
      p00 = fdot2u(t0, hq.x, p00); p01 = fdot2u(t1, hq.y, p01);
      p00 = fdot2u(t2, hq.z, p00); p01 = fdot2u(t3, hq.w, p01);
      p10 = fdot2u(t4, hq.x, p10); p11 = fdot2u(t5, hq.y, p11);
      p10 = fdot2u(t6, hq.z, p10); p11 = fdot2u(t7, hq.w, p11);
    }
    // --- LDS chunks: k 368..511 ---
#pragma unroll
    for (int q = 0; q < 9; ++q){
      uint4 hq = h4[23+q];
      uint4 wa = lws[q][0][j];                     // lane-contiguous: conflict-free
      uint4 wb = lws[q][1][j];
      p00 = fdot2u(wa.x, hq.x, p00); p01 = fdot2u(wa.y, hq.y, p01);
      p00 = fdot2u(wa.z, hq.z, p00); p01 = fdot2u(wa.w, hq.w, p01);
      p10 = fdot2u(wb.x, hq.x, p10); p11 = fdot2u(wb.y, hq.y, p11);
      p10 = fdot2u(wb.z, hq.z, p10); p11 = fdot2u(wb.w, hq.w, p11);
    }
    float a0 = p00 + p01;                          // i (j<256) or f (j>=256)
    float a1 = p10 + p11;                          // g (j<256) or o (j>=256)
    if (j >= 256){ *(float2*)gts2[j-256] = make_float2(a0, a1); }
    __syncthreads();                               // gates visible; h reads done
    if (j < 256){
      float2 fo = *(const float2*)gts2[j];
      c = sigm(fo.x)*c + sigm(a0)*tanh_(a1);
      float h = sigm(fo.y)*tanh_(c);
      __half hh = __float2half(h);
      h2s[j] = hh;
      hs[((size_t)b*NT + t)*NH + j] = hh;
    }
    if (doX) xb[(t+1) & 1][j-256] = pk2(xna, xnc);
    __syncthreads();                               // new h visible
  }
}

// ---------------- projection + loss: f16 MFMA GEMM (M=128 tile, N=256, K=384) ----------------
struct __align__(16) SMp {
  union {
    struct { __half As[128][72]; __half Bs[256][72]; } s;   // staged tiles (pad 64->72)
    __half Zs[128][264];                                    // relu output (pad 256->264)
  } u;
  unsigned wout[16][128];
  float bnl[256];
  float bout[16];
  float logit[128][16];
  float red[128];
};

__global__ __launch_bounds__(512, 2)
void k_proj(const unsigned char* __restrict__ ws,
            const int* __restrict__ labels, const int* __restrict__ lengths,
            const float* __restrict__ bnl, const float* __restrict__ bout,
            float* __restrict__ out){
  __shared__ SMp sm;
  int tid = threadIdx.x;
  int mt = blockIdx.x;
  int m0 = mt*128;
  int b  = m0 >> 10;
  int t0 = m0 & 1023;
  const __half* hs      = (const __half*)(ws + WS_HS);
  const unsigned* latf  = (const unsigned*)(ws + WS_LATF);
  const unsigned* wnl   = (const unsigned*)(ws + WS_WNL);
  const unsigned* woutg = (const unsigned*)(ws + WS_WOUT);

  for (int i = tid; i < 2048; i += 512) ((unsigned*)sm.wout)[i] = woutg[i];
  if (tid < 256) sm.bnl[tid] = bnl[tid];
  if (tid < 16)  sm.bout[tid] = (tid < NV)? bout[tid] : 0.f;

  int wave = tid >> 6, lane = tid & 63;
  int wm = wave >> 2, wn = wave & 3;        // 2 x 4 wave grid, 64x64 per wave
  int l15 = lane & 15, l4 = lane >> 4;

  f32x4 acc[4][4];
  f32x4 zz = {0.f,0.f,0.f,0.f};
#pragma unroll
  for (int a = 0; a < 4; ++a)
#pragma unroll
    for (int q = 0; q < 4; ++q) acc[a][q] = zz;

#pragma unroll 1
  for (int kt = 0; kt < 6; ++kt){
#pragma unroll
    for (int it = 0; it < 2; ++it){           // stage A: 128 rows x 64 k (f16)
      int idx = it*512 + tid;
      int r = idx >> 3, ck = idx & 7;
      int k = kt*64 + ck*8;
      uint4 val;
      if (k < 256) val = *(const uint4*)&hs[((size_t)(m0+r))*NH + k];
      else         val = *(const uint4*)&latf[b*64 + (k-256)/2];
      *(uint4*)&sm.u.s.As[r][ck*8] = val;
    }
#pragma unroll
    for (int it = 0; it < 4; ++it){           // stage B: W_nl 256 rows x 64 k
      int idx = it*512 + tid;
      int n = idx >> 3, ck = idx & 7;
      int k = kt*64 + ck*8;
      uint4 val = *(const uint4*)&wnl[n*192 + k/2];
      *(uint4*)&sm.u.s.Bs[n][ck*8] = val;
    }
    __syncthreads();
#pragma unroll
    for (int kk = 0; kk < 2; ++kk){
      f16x8 af[4], bf[4];
#pragma unroll
      for (int mf = 0; mf < 4; ++mf) af[mf] = *(const f16x8*)&sm.u.s.As[wm*64+mf*16+l15][kk*32+l4*8];
#pragma unroll
      for (int nf = 0; nf < 4; ++nf) bf[nf] = *(const f16x8*)&sm.u.s.Bs[wn*64+nf*16+l15][kk*32+l4*8];
#pragma unroll
      for (int mf = 0; mf < 4; ++mf)
#pragma unroll
        for (int nf = 0; nf < 4; ++nf)
          acc[mf][nf] = __builtin_amdgcn_mfma_f32_16x16x32_f16(af[mf], bf[nf], acc[mf][nf], 0, 0, 0);
    }
    __syncthreads();
  }

  // epilogue: bias + relu -> Zs (f16)
#pragma unroll
  for (int mf = 0; mf < 4; ++mf)
#pragma unroll
    for (int nf = 0; nf < 4; ++nf)
#pragma unroll
      for (int e = 0; e < 4; ++e){
        int row = wm*64 + mf*16 + l4*4 + e;
        int col = wn*64 + nf*16 + l15;
        float v = acc[mf][nf][e] + sm.bnl[col];
        v = v > 0.f ? v : 0.f;
        sm.u.Zs[row][col] = __float2half(v);
      }
  __syncthreads();

  // GEMV: logits[r][v] = Z[r,:] . W_out[v,:] + b_out[v]; 4 threads per row, 4 v's each
  int r = tid >> 2, q = tid & 3;
  float la0 = sm.bout[q], la1 = sm.bout[q+4], la2 = sm.bout[q+8], la3 = sm.bout[q+12];
#pragma unroll
  for (int c8 = 0; c8 < 32; ++c8){
    uint4 zv = *(const uint4*)&sm.u.Zs[r][c8*8];
    uint4 w0 = *(const uint4*)&sm.wout[q][c8*4];
    uint4 w1 = *(const uint4*)&sm.wout[q+4][c8*4];
    uint4 w2 = *(const uint4*)&sm.wout[q+8][c8*4];
    uint4 w3 = *(const uint4*)&sm.wout[q+12][c8*4];
    la0 = fdot2u(w0.x, zv.x, la0); la0 = fdot2u(w0.y, zv.y, la0);
    la0 = fdot2u(w0.z, zv.z, la0); la0 = fdot2u(w0.w, zv.w, la0);
    la1 = fdot2u(w1.x, zv.x, la1); la1 = fdot2u(w1.y, zv.y, la1);
    la1 = fdot2u(w1.z, zv.z, la1); la1 = fdot2u(w1.w, zv.w, la1);
    la2 = fdot2u(w2.x, zv.x, la2); la2 = fdot2u(w2.y, zv.y, la2);
    la2 = fdot2u(w2.z, zv.z, la2); la2 = fdot2u(w2.w, zv.w, la2);
    la3 = fdot2u(w3.x, zv.x, la3); la3 = fdot2u(w3.y, zv.y, la3);
    la3 = fdot2u(w3.z, zv.z, la3); la3 = fdot2u(w3.w, zv.w, la3);
  }
  sm.logit[r][q] = la0; sm.logit[r][q+4] = la1; sm.logit[r][q+8] = la2; sm.logit[r][q+12] = la3;
  __syncthreads();

  if (tid < 128){
    int t = t0 + tid;
    float mx = -1e30f;
#pragma unroll
    for (int v = 0; v < NV; ++v) mx = fmaxf(mx, sm.logit[tid][v]);
    float s = 0.f;
#pragma unroll
    for (int v = 0; v < NV; ++v) s += __expf(sm.logit[tid][v] - mx);
    float lse = mx + __logf(s);
    int lab = labels[b*NT + t];
    float nll = lse - sm.logit[tid][lab];
    sm.red[tid] = (t < lengths[b])? nll : 0.f;
  }
  __syncthreads();
  if (tid < 64){
    float v = sm.red[tid] + sm.red[tid+64];
#pragma unroll
    for (int off = 32; off > 0; off >>= 1) v += __shfl_down(v, off);
    if (tid == 0) atomicAdd(out + b, v);
  }
}

extern "C" void kernel_launch(void* const* d_in, const int* in_sizes, int n_in,
                              void* d_out, int out_size, void* d_ws, size_t ws_size,
                              hipStream_t stream){
  const float* seq   = (const float*)d_in[0];
  const float* lat   = (const float*)d_in[1];
  const int* labels  = (const int*)d_in[2];
  const int* lengths = (const int*)d_in[3];
  const float* Wlat  = (const float*)d_in[4];
  const float* blat  = (const float*)d_in[5];
  const float* Wih   = (const float*)d_in[6];
  const float* Whh   = (const float*)d_in[7];
  const float* bih   = (const float*)d_in[8];
  const float* bhh   = (const float*)d_in[9];
  const float* Wnl   = (const float*)d_in[10];
  const float* bnl   = (const float*)d_in[11];
  const float* Wout  = (const float*)d_in[12];
  const float* bout  = (const float*)d_in[13];
  float* out = (float*)d_out;
  unsigned char* ws = (unsigned char*)d_ws;

  hipLaunchKernelGGL(k_prep, dim3(1281), dim3(128), 0, stream, Wih, Whh, bih, bhh, Wnl, Wout, ws);
  hipLaunchKernelGGL(k_init, dim3(256), dim3(256), 0, stream, lat, Wlat, blat, ws, out);
  hipLaunchKernelGGL(k_lstm, dim3(256), dim3(512), 0, stream, seq, ws);
  hipLaunchKernelGGL(k_proj, dim3(2048), dim3(512), 0, stream, ws, labels, lengths, bnl, bout, out);
}

// Round 7
// 2590.506 us; speedup vs baseline: 15.2277x; 1.1468x over previous
//
#include <hip/hip_runtime.h>
#include <hip/hip_fp16.h>

#define NB 256
#define NT 1024
#define NH 256
#define NL 128
#define NV 13

typedef _Float16 h2t __attribute__((ext_vector_type(2)));
typedef _Float16 f16x8 __attribute__((ext_vector_type(8)));
typedef float f32x4 __attribute__((ext_vector_type(4)));

#define WS_WHH   0x0u       // u32[1024][128]  512KB  packed f16 W_hh
#define WS_WIH   0x80000u   // u32[1024][8]    32KB   packed f16 W_ih (padded 13->16)
#define WS_BIAS  0x88000u   // f32[1024]       4KB    b_ih+b_hh
#define WS_H0F   0x89000u   // f16[256][256]   128KB  h0
#define WS_LATF  0xA9000u   // u32[256][64]    64KB   packed f16 latent
#define WS_WNL   0xB9000u   // u32[256][192]   192KB  packed f16 W_nl
#define WS_WOUT  0xE9000u   // u32[16][128]    8KB    packed f16 W_out (padded 13->16 rows)
#define WS_HS    0x100000u  // f16[256][1024][256] = 128MB hidden states

__device__ __forceinline__ unsigned pk2(float a, float b){
  union { h2t h; unsigned u; } u;
  u.h.x = (_Float16)a; u.h.y = (_Float16)b;
  return u.u;
}

__device__ __forceinline__ float fdot2u(unsigned a, unsigned b, float c){
  union { unsigned u; h2t h; } ua, ub;
  ua.u = a; ub.u = b;
  return __builtin_amdgcn_fdot2(ua.h, ub.h, c, false);
}

__device__ __forceinline__ float sigm(float x){ return __builtin_amdgcn_rcpf(1.f + __expf(-x)); }
__device__ __forceinline__ float tanh_(float x){ return 2.f*__builtin_amdgcn_rcpf(1.f + __expf(-2.f*x)) - 1.f; }

// ---------------- prep: pack weights to f16 ----------------
__global__ void k_prep(const float* __restrict__ Wih, const float* __restrict__ Whh,
                       const float* __restrict__ bih, const float* __restrict__ bhh,
                       const float* __restrict__ Wnl, const float* __restrict__ Wout,
                       unsigned char* __restrict__ ws){
  unsigned* whh = (unsigned*)(ws + WS_WHH);
  unsigned* wih = (unsigned*)(ws + WS_WIH);
  float* bias   = (float*)(ws + WS_BIAS);
  unsigned* wnl = (unsigned*)(ws + WS_WNL);
  unsigned* wout= (unsigned*)(ws + WS_WOUT);
  int blk = blockIdx.x, tid = threadIdx.x;
  if (blk < 1024){
    int r = blk;
    if (tid < 128) whh[r*128+tid] = pk2(Whh[r*256+2*tid], Whh[r*256+2*tid+1]);
    if (tid < 8){
      int k0 = 2*tid, k1 = 2*tid+1;
      float a = (k0 < NV)? Wih[r*NV+k0] : 0.f;
      float b = (k1 < NV)? Wih[r*NV+k1] : 0.f;
      wih[r*8+tid] = pk2(a,b);
    }
    if (tid == 0) bias[r] = bih[r] + bhh[r];
  } else if (blk < 1280){
    int n = blk - 1024;
    for (int i = tid; i < 192; i += 128)
      wnl[n*192+i] = pk2(Wnl[n*384+2*i], Wnl[n*384+2*i+1]);
  } else {
    for (int i = tid; i < 2048; i += 128){
      int v = i >> 7; int p = (i & 127)*2;
      float a = (v < NV)? Wout[v*256+p]   : 0.f;
      float b = (v < NV)? Wout[v*256+p+1] : 0.f;
      wout[i] = pk2(a,b);
    }
  }
}

// ---------------- init: h0 = relu(lat @ W_lat^T + b), pack lat, zero out ----------------
__global__ void k_init(const float* __restrict__ lat, const float* __restrict__ Wlat,
                       const float* __restrict__ blat, unsigned char* __restrict__ ws,
                       float* __restrict__ out){
  __shared__ float sl[NL];
  int b = blockIdx.x, j = threadIdx.x;
  if (j < NL) sl[j] = lat[b*NL+j];
  __syncthreads();
  float a = blat[j];
  for (int k = 0; k < NL; ++k) a += Wlat[j*NL+k]*sl[k];
  float h0 = a > 0.f ? a : 0.f;
  __half* h0h    = (__half*)(ws + WS_H0F);
  unsigned* latf = (unsigned*)(ws + WS_LATF);
  h0h[b*256+j] = __float2half(h0);
  if (j < 64)  latf[b*64+j] = pk2(sl[2*j], sl[2*j+1]);
  if (j == 0)  out[b] = 0.f;
}

// ---------------- recurrent LSTM: 1 WG (512 thr, 8 waves = 2/SIMD) per batch ----------------
// Thread j owns rows r0=j (i if j<256, f else) and r1=j+512 (g / o).
// W_hh row = 32 uint4 packed f16, split per row for a 128V+128A per-wave budget:
//   chunks 0..6   -> arch VGPRs (56 regs, component-pinned)
//   chunks 7..22  -> AGPRs (128 AGPRs exactly)
//   chunks 23..31 -> LDS (147KB, lane-contiguous conflict-free)
// h path (NEW): h staged per-lane with 2 ds_read_b32/wave, broadcast via
// v_readlane -> SGPR, consumed directly as dot2 src (1 SGPR operand legal).
// Kills the 32 b128 h-broadcast LDS reads/wave that made r1-r6 LDS-issue-bound.
__global__ __launch_bounds__(512) __attribute__((amdgpu_waves_per_eu(2, 2)))
void k_lstm(const float* __restrict__ seq, unsigned char* __restrict__ ws){
  __shared__ __align__(16) uint4 lws[9][2][512];   // 147456B: [chunk][row-half][tid]
  __shared__ __align__(16) __half h2s[256];        // current h (128 u32)
  __shared__ __align__(8)  float gts2[256][2];     // {f,o} pre-activations
  __shared__ __align__(16) unsigned xb[2][8];      // packed f16 x_t (13 padded to 16)
  int b = blockIdx.x, j = threadIdx.x;
  int lane = j & 63;
  int r0 = j, r1 = j + 512;
  const uint4* whh4 = (const uint4*)(ws + WS_WHH);   // 32 uint4 per row
  const uint4* wih4 = (const uint4*)(ws + WS_WIH);   // 2 uint4 per row
  const float* bias = (const float*)(ws + WS_BIAS);
  const __half* h0h = (const __half*)(ws + WS_H0F);
  __half* hs = (__half*)(ws + WS_HS);

  uint4 wv[2][7];
  unsigned ag[2][16][4];     // AGPR homes: 2*16*4 = 128 AGPRs
  uint4 wx[2][2];
  float bb0, bb1;
#pragma unroll
  for (int rr = 0; rr < 2; ++rr){
    int r = (rr == 0)? r0 : r1;
#pragma unroll
    for (int q = 0; q < 7; ++q) wv[rr][q] = whh4[r*32+q];
#pragma unroll
    for (int q = 0; q < 16; ++q){
      uint4 w = whh4[r*32+7+q];
      asm volatile("v_accvgpr_write_b32 %0, %1" : "=a"(ag[rr][q][0]) : "v"(w.x));
      asm volatile("v_accvgpr_write_b32 %0, %1" : "=a"(ag[rr][q][1]) : "v"(w.y));
      asm volatile("v_accvgpr_write_b32 %0, %1" : "=a"(ag[rr][q][2]) : "v"(w.z));
      asm volatile("v_accvgpr_write_b32 %0, %1" : "=a"(ag[rr][q][3]) : "v"(w.w));
    }
#pragma unroll
    for (int q = 0; q < 9; ++q) lws[q][rr][j] = whh4[r*32+23+q];
    wx[rr][0] = wih4[r*2]; wx[rr][1] = wih4[r*2+1];
  }
  bb0 = bias[r0]; bb1 = bias[r1];
  if (j < 256){
    h2s[j] = h0h[b*256+j];
  }
  if (j >= 256 && j < 264){
    int i2 = j - 256; int k0 = 2*i2;
    const float* xp = seq + (size_t)b*NT*NV;
    float xa = (k0   < NV)? xp[k0]   : 0.f;
    float xc = (k0+1 < NV)? xp[k0+1] : 0.f;
    xb[0][i2] = pk2(xa, xc);
  }
  float c = 0.f;
  // pin arch-VGPR weights as opaque live values (component-wise; zero instructions)
#pragma unroll
  for (int rr = 0; rr < 2; ++rr){
#pragma unroll
    for (int q = 0; q < 7; ++q)
      asm volatile("" : "+v"(wv[rr][q].x), "+v"(wv[rr][q].y), "+v"(wv[rr][q].z), "+v"(wv[rr][q].w));
    asm volatile("" : "+v"(wx[rr][0].x), "+v"(wx[rr][0].y), "+v"(wx[rr][0].z), "+v"(wx[rr][0].w));
    asm volatile("" : "+v"(wx[rr][1].x), "+v"(wx[rr][1].y), "+v"(wx[rr][1].z), "+v"(wx[rr][1].w));
  }
  __syncthreads();
  const unsigned* h32 = (const unsigned*)h2s;

#pragma unroll 1
  for (int t = 0; t < NT; ++t){
    // issue next-x global load early (hides under the step body)
    float xna = 0.f, xnc = 0.f;
    bool doX = (j >= 256 && j < 264) && (t+1 < NT);
    if (doX){
      int k0 = 2*(j-256);
      const float* xp = seq + ((size_t)b*NT + (t+1))*NV;
      xna = (k0   < NV)? xp[k0]   : 0.f;
      xnc = (k0+1 < NV)? xp[k0+1] : 0.f;
    }
    // per-lane h staging: 2 conflict-free ds_read_b32 per wave
    unsigned vh0 = h32[lane];
    unsigned vh1 = h32[lane + 64];
    float p00 = bb0, p01 = 0.f;
    float p10 = bb1, p11 = 0.f;
    {
      const uint4* xc4 = (const uint4*)xb[t & 1];
      uint4 x0 = xc4[0], x1 = xc4[1];
      p00 = fdot2u(wx[0][0].x, x0.x, p00); p01 = fdot2u(wx[0][0].y, x0.y, p01);
      p00 = fdot2u(wx[0][0].z, x0.z, p00); p01 = fdot2u(wx[0][0].w, x0.w, p01);
      p00 = fdot2u(wx[0][1].x, x1.x, p00); p01 = fdot2u(wx[0][1].y, x1.y, p01);
      p00 = fdot2u(wx[0][1].z, x1.z, p00);
      p10 = fdot2u(wx[1][0].x, x0.x, p10); p11 = fdot2u(wx[1][0].y, x0.y, p11);
      p10 = fdot2u(wx[1][0].z, x0.z, p10); p11 = fdot2u(wx[1][0].w, x0.w, p11);
      p10 = fdot2u(wx[1][1].x, x1.x, p10); p11 = fdot2u(wx[1][1].y, x1.y, p11);
      p10 = fdot2u(wx[1][1].z, x1.z, p10);
    }
    // --- arch-VGPR chunks: h u32 0..27 (all in vh0) ---
#pragma unroll
    for (int q = 0; q < 7; ++q){
      unsigned h0 = __builtin_amdgcn_readlane(vh0, 4*q+0);
      unsigned h1 = __builtin_amdgcn_readlane(vh0, 4*q+1);
      unsigned h2 = __builtin_amdgcn_readlane(vh0, 4*q+2);
      unsigned h3 = __builtin_amdgcn_readlane(vh0, 4*q+3);
      p00 = fdot2u(wv[0][q].x, h0, p00); p01 = fdot2u(wv[0][q].y, h1, p01);
      p00 = fdot2u(wv[0][q].z, h2, p00); p01 = fdot2u(wv[0][q].w, h3, p01);
      p10 = fdot2u(wv[1][q].x, h0, p10); p11 = fdot2u(wv[1][q].y, h1, p11);
      p10 = fdot2u(wv[1][q].z, h2, p10); p11 = fdot2u(wv[1][q].w, h3, p11);
    }
    // --- AGPR chunks: h u32 28..91 ---
#pragma unroll
    for (int q = 0; q < 16; ++q){
      const int base = 28 + 4*q;
      unsigned h0 = __builtin_amdgcn_readlane((base+0) < 64 ? vh0 : vh1, (base+0) & 63);
      unsigned h1 = __builtin_amdgcn_readlane((base+1) < 64 ? vh0 : vh1, (base+1) & 63);
      unsigned h2 = __builtin_amdgcn_readlane((base+2) < 64 ? vh0 : vh1, (base+2) & 63);
      unsigned h3 = __builtin_amdgcn_readlane((base+3) < 64 ? vh0 : vh1, (base+3) & 63);
      unsigned t0, t1, t2, t3, t4, t5, t6, t7;
      asm volatile("v_accvgpr_read_b32 %0, %1" : "=v"(t0) : "a"(ag[0][q][0]));
      asm volatile("v_accvgpr_read_b32 %0, %1" : "=v"(t1) : "a"(ag[0][q][1]));
      asm volatile("v_accvgpr_read_b32 %0, %1" : "=v"(t2) : "a"(ag[0][q][2]));
      asm volatile("v_accvgpr_read_b32 %0, %1" : "=v"(t3) : "a"(ag[0][q][3]));
      asm volatile("v_accvgpr_read_b32 %0, %1" : "=v"(t4) : "a"(ag[1][q][0]));
      asm volatile("v_accvgpr_read_b32 %0, %1" : "=v"(t5) : "a"(ag[1][q][1]));
      asm volatile("v_accvgpr_read_b32 %0, %1" : "=v"(t6) : "a"(ag[1][q][2]));
      asm volatile("v_accvgpr_read_b32 %0, %1" : "=v"(t7) : "a"(ag[1][q][3]));
      p00 = fdot2u(t0, h0, p00); p01 = fdot2u(t1, h1, p01);
      p00 = fdot2u(t2, h2, p00); p01 = fdot2u(t3, h3, p01);
      p10 = fdot2u(t4, h0, p10); p11 = fdot2u(t5, h1, p11);
      p10 = fdot2u(t6, h2, p10); p11 = fdot2u(t7, h3, p11);
    }
    // --- LDS chunks: h u32 92..127 (all in vh1) ---
#pragma unroll
    for (int q = 0; q < 9; ++q){
      const int base = 92 + 4*q;
      unsigned h0 = __builtin_amdgcn_readlane(vh1, (base+0) - 64);
      unsigned h1 = __builtin_amdgcn_readlane(vh1, (base+1) - 64);
      unsigned h2 = __builtin_amdgcn_readlane(vh1, (base+2) - 64);
      unsigned h3 = __builtin_amdgcn_readlane(vh1, (base+3) - 64);
      uint4 wa = lws[q][0][j];                     // lane-contiguous: conflict-free
      uint4 wb = lws[q][1][j];
      p00 = fdot2u(wa.x, h0, p00); p01 = fdot2u(wa.y, h1, p01);
      p00 = fdot2u(wa.z, h2, p00); p01 = fdot2u(wa.w, h3, p01);
      p10 = fdot2u(wb.x, h0, p10); p11 = fdot2u(wb.y, h1, p11);
      p10 = fdot2u(wb.z, h2, p10); p11 = fdot2u(wb.w, h3, p11);
    }
    float a0 = p00 + p01;                          // i (j<256) or f (j>=256)
    float a1 = p10 + p11;                          // g (j<256) or o (j>=256)
    if (j >= 256){ *(float2*)gts2[j-256] = make_float2(a0, a1); }
    __syncthreads();                               // gates visible; h reads done
    if (j < 256){
      float2 fo = *(const float2*)gts2[j];
      c = sigm(fo.x)*c + sigm(a0)*tanh_(a1);
      float h = sigm(fo.y)*tanh_(c);
      __half hh = __float2half(h);
      h2s[j] = hh;
      hs[((size_t)b*NT + t)*NH + j] = hh;
    }
    if (doX) xb[(t+1) & 1][j-256] = pk2(xna, xnc);
    __syncthreads();                               // new h visible
  }
}

// ---------------- projection + loss: f16 MFMA GEMM (M=128 tile, N=256, K=384) ----------------
struct __align__(16) SMp {
  union {
    struct { __half As[128][72]; __half Bs[256][72]; } s;   // staged tiles (pad 64->72)
    __half Zs[128][264];                                    // relu output (pad 256->264)
  } u;
  unsigned wout[16][128];
  float bnl[256];
  float bout[16];
  float logit[128][16];
  float red[128];
};

__global__ __launch_bounds__(512, 2)
void k_proj(const unsigned char* __restrict__ ws,
            const int* __restrict__ labels, const int* __restrict__ lengths,
            const float* __restrict__ bnl, const float* __restrict__ bout,
            float* __restrict__ out){
  __shared__ SMp sm;
  int tid = threadIdx.x;
  int mt = blockIdx.x;
  int m0 = mt*128;
  int b  = m0 >> 10;
  int t0 = m0 & 1023;
  const __half* hs      = (const __half*)(ws + WS_HS);
  const unsigned* latf  = (const unsigned*)(ws + WS_LATF);
  const unsigned* wnl   = (const unsigned*)(ws + WS_WNL);
  const unsigned* woutg = (const unsigned*)(ws + WS_WOUT);

  for (int i = tid; i < 2048; i += 512) ((unsigned*)sm.wout)[i] = woutg[i];
  if (tid < 256) sm.bnl[tid] = bnl[tid];
  if (tid < 16)  sm.bout[tid] = (tid < NV)? bout[tid] : 0.f;

  int wave = tid >> 6, lane = tid & 63;
  int wm = wave >> 2, wn = wave & 3;        // 2 x 4 wave grid, 64x64 per wave
  int l15 = lane & 15, l4 = lane >> 4;

  f32x4 acc[4][4];
  f32x4 zz = {0.f,0.f,0.f,0.f};
#pragma unroll
  for (int a = 0; a < 4; ++a)
#pragma unroll
    for (int q = 0; q < 4; ++q) acc[a][q] = zz;

#pragma unroll 1
  for (int kt = 0; kt < 6; ++kt){
#pragma unroll
    for (int it = 0; it < 2; ++it){           // stage A: 128 rows x 64 k (f16)
      int idx = it*512 + tid;
      int r = idx >> 3, ck = idx & 7;
      int k = kt*64 + ck*8;
      uint4 val;
      if (k < 256) val = *(const uint4*)&hs[((size_t)(m0+r))*NH + k];
      else         val = *(const uint4*)&latf[b*64 + (k-256)/2];
      *(uint4*)&sm.u.s.As[r][ck*8] = val;
    }
#pragma unroll
    for (int it = 0; it < 4; ++it){           // stage B: W_nl 256 rows x 64 k
      int idx = it*512 + tid;
      int n = idx >> 3, ck = idx & 7;
      int k = kt*64 + ck*8;
      uint4 val = *(const uint4*)&wnl[n*192 + k/2];
      *(uint4*)&sm.u.s.Bs[n][ck*8] = val;
    }
    __syncthreads();
#pragma unroll
    for (int kk = 0; kk < 2; ++kk){
      f16x8 af[4], bf[4];
#pragma unroll
      for (int mf = 0; mf < 4; ++mf) af[mf] = *(const f16x8*)&sm.u.s.As[wm*64+mf*16+l15][kk*32+l4*8];
#pragma unroll
      for (int nf = 0; nf < 4; ++nf) bf[nf] = *(const f16x8*)&sm.u.s.Bs[wn*64+nf*16+l15][kk*32+l4*8];
#pragma unroll
      for (int mf = 0; mf < 4; ++mf)
#pragma unroll
        for (int nf = 0; nf < 4; ++nf)
          acc[mf][nf] = __builtin_amdgcn_mfma_f32_16x16x32_f16(af[mf], bf[nf], acc[mf][nf], 0, 0, 0);
    }
    __syncthreads();
  }

  // epilogue: bias + relu -> Zs (f16)
#pragma unroll
  for (int mf = 0; mf < 4; ++mf)
#pragma unroll
    for (int nf = 0; nf < 4; ++nf)
#pragma unroll
      for (int e = 0; e < 4; ++e){
        int row = wm*64 + mf*16 + l4*4 + e;
        int col = wn*64 + nf*16 + l15;
        float v = acc[mf][nf][e] + sm.bnl[col];
        v = v > 0.f ? v : 0.f;
        sm.u.Zs[row][col] = __float2half(v);
      }
  __syncthreads();

  // GEMV: logits[r][v] = Z[r,:] . W_out[v,:] + b_out[v]; 4 threads per row, 4 v's each
  int r = tid >> 2, q = tid & 3;
  float la0 = sm.bout[q], la1 = sm.bout[q+4], la2 = sm.bout[q+8], la3 = sm.bout[q+12];
#pragma unroll
  for (int c8 = 0; c8 < 32; ++c8){
    uint4 zv = *(const uint4*)&sm.u.Zs[r][c8*8];
    uint4 w0 = *(const uint4*)&sm.wout[q][c8*4];
    uint4 w1 = *(const uint4*)&sm.wout[q+4][c8*4];
    uint4 w2 = *(const uint4*)&sm.wout[q+8][c8*4];
    uint4 w3 = *(const uint4*)&sm.wout[q+12][c8*4];
    la0 = fdot2u(w0.x, zv.x, la0); la0 = fdot2u(w0.y, zv.y, la0);
    la0 = fdot2u(w0.z, zv.z, la0); la0 = fdot2u(w0.w, zv.w, la0);
    la1 = fdot2u(w1.x, zv.x, la1); la1 = fdot2u(w1.y, zv.y, la1);
    la1 = fdot2u(w1.z, zv.z, la1); la1 = fdot2u(w1.w, zv.w, la1);
    la2 = fdot2u(w2.x, zv.x, la2); la2 = fdot2u(w2.y, zv.y, la2);
    la2 = fdot2u(w2.z, zv.z, la2); la2 = fdot2u(w2.w, zv.w, la2);
    la3 = fdot2u(w3.x, zv.x, la3); la3 = fdot2u(w3.y, zv.y, la3);
    la3 = fdot2u(w3.z, zv.z, la3); la3 = fdot2u(w3.w, zv.w, la3);
  }
  sm.logit[r][q] = la0; sm.logit[r][q+4] = la1; sm.logit[r][q+8] = la2; sm.logit[r][q+12] = la3;
  __syncthreads();

  if (tid < 128){
    int t = t0 + tid;
    float mx = -1e30f;
#pragma unroll
    for (int v = 0; v < NV; ++v) mx = fmaxf(mx, sm.logit[tid][v]);
    float s = 0.f;
#pragma unroll
    for (int v = 0; v < NV; ++v) s += __expf(sm.logit[tid][v] - mx);
    float lse = mx + __logf(s);
    int lab = labels[b*NT + t];
    float nll = lse - sm.logit[tid][lab];
    sm.red[tid] = (t < lengths[b])? nll : 0.f;
  }
  __syncthreads();
  if (tid < 64){
    float v = sm.red[tid] + sm.red[tid+64];
#pragma unroll
    for (int off = 32; off > 0; off >>= 1) v += __shfl_down(v, off);
    if (tid == 0) atomicAdd(out + b, v);
  }
}

extern "C" void kernel_launch(void* const* d_in, const int* in_sizes, int n_in,
                              void* d_out, int out_size, void* d_ws, size_t ws_size,
                              hipStream_t stream){
  const float* seq   = (const float*)d_in[0];
  const float* lat   = (const float*)d_in[1];
  const int* labels  = (const int*)d_in[2];
  const int* lengths = (const int*)d_in[3];
  const float* Wlat  = (const float*)d_in[4];
  const float* blat  = (const float*)d_in[5];
  const float* Wih   = (const float*)d_in[6];
  const float* Whh   = (const float*)d_in[7];
  const float* bih   = (const float*)d_in[8];
  const float* bhh   = (const float*)d_in[9];
  const float* Wnl   = (const float*)d_in[10];
  const float* bnl   = (const float*)d_in[11];
  const float* Wout  = (const float*)d_in[12];
  const float* bout  = (const float*)d_in[13];
  float* out = (float*)d_out;
  unsigned char* ws = (unsigned char*)d_ws;

  hipLaunchKernelGGL(k_prep, dim3(1281), dim3(128), 0, stream, Wih, Whh, bih, bhh, Wnl, Wout, ws);
  hipLaunchKernelGGL(k_init, dim3(256), dim3(256), 0, stream, lat, Wlat, blat, ws, out);
  hipLaunchKernelGGL(k_lstm, dim3(256), dim3(512), 0, stream, seq, ws);
  hipLaunchKernelGGL(k_proj, dim3(2048), dim3(512), 0, stream, ws, labels, lengths, bnl, bout, out);
}